// Round 9
// baseline (248.961 us; speedup 1.0000x reference)
//
#include <hip/hip_runtime.h>

#define DEV __device__ __forceinline__

typedef __bf16 bf16x8 __attribute__((ext_vector_type(8)));
typedef float f32x4 __attribute__((ext_vector_type(4)));
typedef unsigned short u16x8 __attribute__((ext_vector_type(8)));
typedef unsigned int u32;
typedef unsigned long long u64;

// f32 -> bf16 round-to-nearest-even (finite inputs only)
DEV unsigned short f2bf(float f) {
  union { float f; unsigned int u; } v; v.f = f;
  unsigned int r = v.u + 0x7fffu + ((v.u >> 16) & 1u);
  return (unsigned short)(r >> 16);
}

// XOR swizzle for [rows][64 bf16] tiles (row stride 128 B)
DEV int swz(int row, int kbyte) { return row * 128 + (kbyte ^ ((row & 7) << 4)); }

// async global->LDS, 16B per lane; LDS dest = wave-uniform base + lane*16
DEV void gload16(const void* g, void* l) {
  __builtin_amdgcn_global_load_lds(
      (const __attribute__((address_space(1))) unsigned int*)g,
      (__attribute__((address_space(3))) unsigned int*)l, 16, 0, 0);
}

// ---------------- fused prep: mask bitpack + X cast/pack + W transpose/pack ----------------
// flat grid: [0,16384) mask ; [16384,17920) xcast ; [17920,22016) wtrans
__global__ __launch_bounds__(256) void prep_k(
    const int* __restrict__ mask, u32* __restrict__ bits,
    const float* __restrict__ Qx, const float* __restrict__ Kx, const float* __restrict__ Vx,
    unsigned short* __restrict__ qp, unsigned short* __restrict__ kp,
    unsigned short* __restrict__ vp,
    const float* __restrict__ W0, const float* __restrict__ W1,
    const float* __restrict__ W2, const float* __restrict__ W3,
    unsigned short* __restrict__ O0, unsigned short* __restrict__ O1,
    unsigned short* __restrict__ O2, unsigned short* __restrict__ O3) {
  __shared__ float tile[32][33];
  int bid = blockIdx.x, t = threadIdx.x;
  if (bid < 16384) {
    // mask int32 -> bitmask, causal folded in
    int e = bid * 256 + t;                  // over B*S*S
    int k = e & 1023, q = (e >> 10) & 1023;
    int m = (mask[e] != 0) && (k <= q);
    unsigned long long b = __ballot(m);
    int lane = t & 63;
    if (lane == 0)       bits[e >> 5] = (u32)b;
    else if (lane == 32) bits[e >> 5] = (u32)(b >> 32);
  } else if (bid < 17920) {
    // X f32 [4096][1024] -> packed pre-swizzled bf16 tiles (16384 B each)
    int r2 = bid - 16384;
    int z = r2 >> 9, tl = r2 & 511;         // tl = mb*16 + kt
    const float* X = z == 0 ? Qx : z == 1 ? Kx : Vx;
    unsigned short* P = z == 0 ? qp : z == 1 ? kp : vp;
    int mb = tl >> 4, kt = tl & 15;
    size_t tb = (size_t)tl * 16384;
    #pragma unroll
    for (int i = 0; i < 4; i++) {
      int idx = i * 256 + t;                // 0..1023 = r*8 + j
      int r = idx >> 3, j = idx & 7;
      int c0 = ((j * 16) ^ ((r & 7) << 4)) >> 1;
      const float* src = X + (size_t)(mb * 128 + r) * 1024 + kt * 64 + c0;
      f32x4 a = *(const f32x4*)src;
      f32x4 bq = *(const f32x4*)(src + 4);
      u16x8 o;
      o[0] = f2bf(a[0]); o[1] = f2bf(a[1]); o[2] = f2bf(a[2]); o[3] = f2bf(a[3]);
      o[4] = f2bf(bq[0]); o[5] = f2bf(bq[1]); o[6] = f2bf(bq[2]); o[7] = f2bf(bq[3]);
      *(u16x8*)((char*)P + tb + (size_t)idx * 16) = o;
    }
  } else {
    // W [K][N] f32 -> packed pre-swizzled W^T tiles
    int r2 = bid - 17920;
    int z = r2 >> 10, rem = r2 & 1023;
    const float* W = z == 0 ? W0 : z == 1 ? W1 : z == 2 ? W2 : W3;
    unsigned short* O = z == 0 ? O0 : z == 1 ? O1 : z == 2 ? O2 : O3;
    int tx = t & 31, ty = t >> 5;           // 32 x 8
    int x0 = (rem & 31) * 32, y0 = (rem >> 5) * 32;   // x: n, y: k
    #pragma unroll
    for (int i = 0; i < 4; i++)
      tile[ty + i * 8][tx] = W[(size_t)(y0 + ty + i * 8) * 1024 + x0 + tx];
    __syncthreads();
    #pragma unroll
    for (int i = 0; i < 4; i++) {
      int n = x0 + ty + i * 8, k = y0 + tx;
      size_t a = (size_t)((n >> 7) * 16 + (k >> 6)) * 16384 + swz(n & 127, (k & 63) * 2);
      *(unsigned short*)((char*)O + a) = f2bf(tile[tx][ty + i * 8]);
    }
  }
}

// ---------------- projection GEMM (packed A,B via global_load_lds) ----------------
// z=0: Q -> row-major [B,H,S,dk]; z=1: K -> packed 64x64 tiles; z=2: V^T -> packed
__global__ __launch_bounds__(256) void proj_gemm_k(
    const unsigned short* __restrict__ Qp, const unsigned short* __restrict__ Kp,
    const unsigned short* __restrict__ Vp,
    const unsigned short* __restrict__ Wtq, const unsigned short* __restrict__ Wtk,
    const unsigned short* __restrict__ Wtv,
    unsigned short* __restrict__ qo, unsigned short* __restrict__ ko,
    unsigned short* __restrict__ vo) {
  int z = blockIdx.z;
  const unsigned short* Ap = z == 0 ? Qp : z == 1 ? Kp : Vp;
  const unsigned short* Bp = z == 0 ? Wtq : z == 1 ? Wtk : Wtv;
  unsigned short* out = z == 0 ? qo : z == 1 ? ko : vo;

  __shared__ __align__(16) unsigned short As[8192];
  __shared__ __align__(16) unsigned short Bs[8192];

  int t = threadIdx.x, w = t >> 6, lane = t & 63;
  int wm = (w >> 1) * 64, wn = (w & 1) * 64;
  int rl = lane & 15, kgrp = lane >> 4;

  f32x4 acc[4][4];
  #pragma unroll
  for (int m = 0; m < 4; m++)
    #pragma unroll
    for (int n = 0; n < 4; n++)
      #pragma unroll
      for (int r = 0; r < 4; r++) acc[m][n][r] = 0.f;

  for (int kt = 0; kt < 16; kt++) {
    __syncthreads();
    const char* ab = (const char*)Ap + (size_t)(blockIdx.x * 16 + kt) * 16384 + w * 1024 + lane * 16;
    const char* bb = (const char*)Bp + (size_t)(blockIdx.y * 16 + kt) * 16384 + w * 1024 + lane * 16;
    char* al = (char*)As + w * 1024;
    char* bl = (char*)Bs + w * 1024;
    #pragma unroll
    for (int i = 0; i < 4; i++) {
      gload16(ab + i * 4096, al + i * 4096);
      gload16(bb + i * 4096, bl + i * 4096);
    }
    __syncthreads();
    #pragma unroll
    for (int kk = 0; kk < 2; kk++) {
      bf16x8 af[4], bfr[4];
      #pragma unroll
      for (int m = 0; m < 4; m++)
        af[m] = *(const bf16x8*)((const char*)As + swz(wm + m * 16 + rl, kk * 64 + kgrp * 16));
      #pragma unroll
      for (int n = 0; n < 4; n++)
        bfr[n] = *(const bf16x8*)((const char*)Bs + swz(wn + n * 16 + rl, kk * 64 + kgrp * 16));
      #pragma unroll
      for (int m = 0; m < 4; m++)
        #pragma unroll
        for (int n = 0; n < 4; n++)
          acc[m][n] = __builtin_amdgcn_mfma_f32_16x16x32_bf16(af[m], bfr[n], acc[m][n], 0, 0, 0);
    }
  }
  int m0 = blockIdx.x * 128, n0 = blockIdx.y * 128;
  #pragma unroll
  for (int m = 0; m < 4; m++)
    #pragma unroll
    for (int n = 0; n < 4; n++)
      #pragma unroll
      for (int r = 0; r < 4; r++) {
        int grow = m0 + wm + m * 16 + kgrp * 4 + r;
        int gcol = n0 + wn + n * 16 + rl;
        int b = grow >> 10, s = grow & 1023;
        int h = gcol >> 6, d = gcol & 63;
        unsigned short val = f2bf(acc[m][n][r]);
        if (z == 0) {
          out[(size_t)((b * 16 + h) * 1024 + s) * 64 + d] = val;
        } else if (z == 1) {       // K packed: tile (bh, s>>6), row s&63, col d
          *(unsigned short*)((char*)out +
            (size_t)((b * 16 + h) * 16 + (s >> 6)) * 8192 + swz(s & 63, d * 2)) = val;
        } else {                   // V^T packed: tile (bh, s>>6), row d, col s&63
          *(unsigned short*)((char*)out +
            (size_t)((b * 16 + h) * 16 + (s >> 6)) * 8192 + swz(d, (s & 63) * 2)) = val;
        }
      }
}

// ---------------- fused masked-causal flash attention (1 q-tile/block) ----------------
// No-max softmax: p = keep ? exp(s/8) : 0; per-lane partial row sums, one reduce at end.
// Heaviest q-tiles dispatched first (LPT). 4 blocks/CU by LDS (40KB).
__global__ __launch_bounds__(256) void attn_k(
    const unsigned short* __restrict__ qg, const unsigned short* __restrict__ kp,
    const unsigned short* __restrict__ vp, const u32* __restrict__ mbits,
    unsigned short* __restrict__ ccp) {
  int qt = 15 - (int)blockIdx.x;     // heaviest first
  int bh = blockIdx.y;               // 0..63
  int b = bh >> 4, h = bh & 15;
  int t = threadIdx.x, w = t >> 6, lane = t & 63;
  int rl = lane & 15, kgrp = lane >> 4;

  const int J = qt + 1;
  const int q0 = qt * 64;

  __shared__ __align__(16) unsigned short Ks[2][4096];
  __shared__ __align__(16) unsigned short Vs[2][4096];   // [d][kv]
  __shared__ __align__(16) unsigned short Ps[4][1024];

  const size_t qoff = (size_t)bh * 65536;
  const char* kbase = (const char*)kp + (size_t)bh * 131072;
  const char* vbase = (const char*)vp + (size_t)bh * 131072;

  // Q fragments direct from global (contiguous 16B per lane)
  bf16x8 qa[2];
  {
    int row = q0 + w * 16 + rl;
    #pragma unroll
    for (int kk = 0; kk < 2; kk++)
      qa[kk] = *(const bf16x8*)(qg + qoff + (size_t)row * 64 + kk * 32 + kgrp * 8);
  }

  // prologue: stage tile 0 into buf 0
  {
    const char* kg = kbase + w * 1024 + lane * 16;
    const char* vg = vbase + w * 1024 + lane * 16;
    char* kl = (char*)Ks[0] + w * 1024;
    char* vl = (char*)Vs[0] + w * 1024;
    gload16(kg, kl); gload16(kg + 4096, kl + 4096);
    gload16(vg, vl); gload16(vg + 4096, vl + 4096);
  }

  float lsum[4];
  f32x4 acc[4];
  #pragma unroll
  for (int r = 0; r < 4; r++) {
    lsum[r] = 0.f;
    #pragma unroll
    for (int d = 0; d < 4; d++) acc[d][r] = 0.f;
  }

  for (int j = 0; j < J; j++) {
    __syncthreads();   // vmcnt(0) drain: tile j resident; prev-iter reads done
    if (j + 1 < J) {
      int nb = (j + 1) & 1;
      const char* kg = kbase + (size_t)(j + 1) * 8192 + w * 1024 + lane * 16;
      const char* vg = vbase + (size_t)(j + 1) * 8192 + w * 1024 + lane * 16;
      char* kl = (char*)Ks[nb] + w * 1024;
      char* vl = (char*)Vs[nb] + w * 1024;
      gload16(kg, kl); gload16(kg + 4096, kl + 4096);
      gload16(vg, vl); gload16(vg + 4096, vl + 4096);
    }
    const char* Kb = (const char*)Ks[j & 1];
    const char* Vb = (const char*)Vs[j & 1];

    // S = Q K^T (raw q.k; scale folded into exp arg)
    f32x4 sc[4];
    #pragma unroll
    for (int n = 0; n < 4; n++) {
      f32x4 z4;
      #pragma unroll
      for (int r = 0; r < 4; r++) z4[r] = 0.f;
      bf16x8 kb0 = *(const bf16x8*)(Kb + swz(n * 16 + rl, 0 * 64 + kgrp * 16));
      bf16x8 kb1 = *(const bf16x8*)(Kb + swz(n * 16 + rl, 1 * 64 + kgrp * 16));
      z4 = __builtin_amdgcn_mfma_f32_16x16x32_bf16(qa[0], kb0, z4, 0, 0, 0);
      sc[n] = __builtin_amdgcn_mfma_f32_16x16x32_bf16(qa[1], kb1, z4, 0, 0, 0);
    }
    // mask bits (causal pre-folded); exact-zero -> weight 0 quirk
    u32 b0[4], b1[4];
    #pragma unroll
    for (int r = 0; r < 4; r++) {
      int qrow = q0 + w * 16 + kgrp * 4 + r;
      u64 mw = *(const u64*)(mbits + ((size_t)(b * 1024 + qrow) * 32 + j * 2));
      b0[r] = (u32)mw >> rl;
      b1[r] = (u32)(mw >> 32) >> rl;
    }
    const float C = 0.18033688011112042f;   // 0.125 * log2(e)
    float pe[4][4];
    #pragma unroll
    for (int n = 0; n < 4; n++) {
      #pragma unroll
      for (int r = 0; r < 4; r++) {
        u32 bit = ((n & 2) ? b1[r] : b0[r]) >> ((n & 1) << 4);
        float ex = exp2f(sc[n][r] * C);
        bool keep = (bit & 1u) && (sc[n][r] != 0.f);
        pe[n][r] = keep ? ex : 0.f;
      }
    }
    #pragma unroll
    for (int r = 0; r < 4; r++)
      lsum[r] += (pe[0][r] + pe[1][r]) + (pe[2][r] + pe[3][r]);
    // P -> per-wave LDS buffer (wave-internal ordering only; no barrier)
    unsigned short* pb = &Ps[w][0];
    #pragma unroll
    for (int n = 0; n < 4; n++) {
      int col = n * 16 + rl;
      #pragma unroll
      for (int r = 0; r < 4; r++)
        *(unsigned short*)((char*)pb + swz(kgrp * 4 + r, col * 2)) = f2bf(pe[n][r]);
    }
    bf16x8 pa[2];
    #pragma unroll
    for (int kk = 0; kk < 2; kk++)
      pa[kk] = *(const bf16x8*)((const char*)pb + swz(rl, kk * 64 + kgrp * 16));
    #pragma unroll
    for (int d = 0; d < 4; d++) {
      bf16x8 vb0 = *(const bf16x8*)(Vb + swz(d * 16 + rl, 0 * 64 + kgrp * 16));
      bf16x8 vb1 = *(const bf16x8*)(Vb + swz(d * 16 + rl, 1 * 64 + kgrp * 16));
      acc[d] = __builtin_amdgcn_mfma_f32_16x16x32_bf16(pa[0], vb0, acc[d], 0, 0, 0);
      acc[d] = __builtin_amdgcn_mfma_f32_16x16x32_bf16(pa[1], vb1, acc[d], 0, 0, 0);
    }
  }
  // epilogue: reduce row sums across the 16-lane group, scale, store packed cc
  #pragma unroll
  for (int r = 0; r < 4; r++) {
    float l = lsum[r];
    l += __shfl_xor(l, 1); l += __shfl_xor(l, 2);
    l += __shfl_xor(l, 4); l += __shfl_xor(l, 8);
    float linv = 1.f / l;
    int srow = q0 + w * 16 + kgrp * 4 + r;
    int grow = b * 1024 + srow;
    char* tbase = (char*)ccp + (size_t)((grow >> 7) * 16 + h) * 16384;
    int rr = grow & 127;
    #pragma unroll
    for (int d = 0; d < 4; d++)
      *(unsigned short*)(tbase + swz(rr, (d * 16 + rl) * 2)) = f2bf(acc[d][r] * linv);
  }
}

// ---------------- output GEMM: out = cc(packed) @ Wot^T + bo, f32 out ----------------
__global__ __launch_bounds__(256) void out_gemm_k(
    const unsigned short* __restrict__ Ap, const unsigned short* __restrict__ Bp,
    const float* __restrict__ bias, float* __restrict__ out) {
  __shared__ __align__(16) unsigned short As[8192];
  __shared__ __align__(16) unsigned short Bs[8192];

  int t = threadIdx.x, w = t >> 6, lane = t & 63;
  int wm = (w >> 1) * 64, wn = (w & 1) * 64;
  int rl = lane & 15, kgrp = lane >> 4;

  f32x4 acc[4][4];
  #pragma unroll
  for (int m = 0; m < 4; m++)
    #pragma unroll
    for (int n = 0; n < 4; n++)
      #pragma unroll
      for (int r = 0; r < 4; r++) acc[m][n][r] = 0.f;

  for (int kt = 0; kt < 16; kt++) {
    __syncthreads();
    const char* ab = (const char*)Ap + (size_t)(blockIdx.x * 16 + kt) * 16384 + w * 1024 + lane * 16;
    const char* bb = (const char*)Bp + (size_t)(blockIdx.y * 16 + kt) * 16384 + w * 1024 + lane * 16;
    char* al = (char*)As + w * 1024;
    char* bl = (char*)Bs + w * 1024;
    #pragma unroll
    for (int i = 0; i < 4; i++) {
      gload16(ab + i * 4096, al + i * 4096);
      gload16(bb + i * 4096, bl + i * 4096);
    }
    __syncthreads();
    #pragma unroll
    for (int kk = 0; kk < 2; kk++) {
      bf16x8 af[4], bfr[4];
      #pragma unroll
      for (int m = 0; m < 4; m++)
        af[m] = *(const bf16x8*)((const char*)As + swz(wm + m * 16 + rl, kk * 64 + kgrp * 16));
      #pragma unroll
      for (int n = 0; n < 4; n++)
        bfr[n] = *(const bf16x8*)((const char*)Bs + swz(wn + n * 16 + rl, kk * 64 + kgrp * 16));
      #pragma unroll
      for (int m = 0; m < 4; m++)
        #pragma unroll
        for (int n = 0; n < 4; n++)
          acc[m][n] = __builtin_amdgcn_mfma_f32_16x16x32_bf16(af[m], bfr[n], acc[m][n], 0, 0, 0);
    }
  }
  int m0 = blockIdx.x * 128, n0 = blockIdx.y * 128;
  #pragma unroll
  for (int m = 0; m < 4; m++)
    #pragma unroll
    for (int n = 0; n < 4; n++)
      #pragma unroll
      for (int r = 0; r < 4; r++) {
        int grow = m0 + wm + m * 16 + kgrp * 4 + r;
        int gcol = n0 + wn + n * 16 + rl;
        out[(size_t)grow * 1024 + gcol] = acc[m][n][r] + bias[gcol];
      }
}

extern "C" void kernel_launch(void* const* d_in, const int* in_sizes, int n_in,
                              void* d_out, int out_size, void* d_ws, size_t ws_size,
                              hipStream_t stream) {
  const float* Q  = (const float*)d_in[0];
  const float* K  = (const float*)d_in[1];
  const float* V  = (const float*)d_in[2];
  const int* mask = (const int*)d_in[3];
  const float* Wq = (const float*)d_in[4];
  const float* Wk = (const float*)d_in[5];
  const float* Wv = (const float*)d_in[6];
  const float* Wo = (const float*)d_in[7];
  const float* bo = (const float*)d_in[8];
  float* out = (float*)d_out;

  char* ws = (char*)d_ws;
  unsigned short* xq  = (unsigned short*)(ws);                  // 8 MB packed X_Q (dead after proj)
  unsigned short* xk  = (unsigned short*)(ws + (8u  << 20));    // 8 MB packed X_K
  unsigned short* xv  = (unsigned short*)(ws + (16u << 20));    // 8 MB packed X_V
  unsigned short* ccp = (unsigned short*)(ws);                  // 8 MB packed cc (aliases xq)
  unsigned short* qb  = (unsigned short*)(ws + (24u << 20));    // 8 MB q row-major [B,H,S,dk]
  unsigned short* kpk = (unsigned short*)(ws + (32u << 20));    // 8 MB k packed tiles
  unsigned short* vpk = (unsigned short*)(ws + (40u << 20));    // 8 MB v^T packed tiles
  unsigned short* wqt = (unsigned short*)(ws + (48u << 20));    // 2 MB each, packed
  unsigned short* wkt = (unsigned short*)(ws + (50u << 20));
  unsigned short* wvt = (unsigned short*)(ws + (52u << 20));
  unsigned short* wot = (unsigned short*)(ws + (54u << 20));
  u32*            mb  = (u32*)(ws + (56u << 20));               // 512 KB

  prep_k<<<22016, 256, 0, stream>>>(mask, mb, Q, K, V, xq, xk, xv,
                                    Wq, Wk, Wv, Wo, wqt, wkt, wvt, wot);
  proj_gemm_k<<<dim3(32, 8, 3), 256, 0, stream>>>(xq, xk, xv, wqt, wkt, wvt, qb, kpk, vpk);
  attn_k<<<dim3(16, 64), 256, 0, stream>>>(qb, kpk, vpk, mb, ccp);
  out_gemm_k<<<dim3(32, 8), 256, 0, stream>>>(ccp, wot, bo, out);
}

// Round 10
// 246.923 us; speedup vs baseline: 1.0083x; 1.0083x over previous
//
#include <hip/hip_runtime.h>

#define DEV __device__ __forceinline__

typedef __bf16 bf16x8 __attribute__((ext_vector_type(8)));
typedef float f32x4 __attribute__((ext_vector_type(4)));
typedef unsigned short u16x8 __attribute__((ext_vector_type(8)));
typedef unsigned int u32;
typedef unsigned long long u64;

// f32 -> bf16 round-to-nearest-even (finite inputs only)
DEV unsigned short f2bf(float f) {
  union { float f; unsigned int u; } v; v.f = f;
  unsigned int r = v.u + 0x7fffu + ((v.u >> 16) & 1u);
  return (unsigned short)(r >> 16);
}

// XOR swizzle for [rows][64 bf16] tiles (row stride 128 B)
DEV int swz(int row, int kbyte) { return row * 128 + (kbyte ^ ((row & 7) << 4)); }
// XOR swizzle for [rows][128 bf16] tiles (row stride 256 B)
DEV int swzV(int row, int kbyte) { return row * 256 + (kbyte ^ ((row & 7) << 4)); }

// async global->LDS, 16B per lane; LDS dest = wave-uniform base + lane*16
DEV void gload16(const void* g, void* l) {
  __builtin_amdgcn_global_load_lds(
      (const __attribute__((address_space(1))) unsigned int*)g,
      (__attribute__((address_space(3))) unsigned int*)l, 16, 0, 0);
}

// ---------------- fused prep: mask bitpack + X cast/pack + W transpose/pack ----------------
// flat grid: [0,16384) mask ; [16384,17920) xcast ; [17920,22016) wtrans
__global__ __launch_bounds__(256) void prep_k(
    const int* __restrict__ mask, u32* __restrict__ bits,
    const float* __restrict__ Qx, const float* __restrict__ Kx, const float* __restrict__ Vx,
    unsigned short* __restrict__ qp, unsigned short* __restrict__ kp,
    unsigned short* __restrict__ vp,
    const float* __restrict__ W0, const float* __restrict__ W1,
    const float* __restrict__ W2, const float* __restrict__ W3,
    unsigned short* __restrict__ O0, unsigned short* __restrict__ O1,
    unsigned short* __restrict__ O2, unsigned short* __restrict__ O3) {
  __shared__ float tile[32][33];
  int bid = blockIdx.x, t = threadIdx.x;
  if (bid < 16384) {
    // mask int32 -> bitmask, causal folded in
    int e = bid * 256 + t;                  // over B*S*S
    int k = e & 1023, q = (e >> 10) & 1023;
    int m = (mask[e] != 0) && (k <= q);
    unsigned long long b = __ballot(m);
    int lane = t & 63;
    if (lane == 0)       bits[e >> 5] = (u32)b;
    else if (lane == 32) bits[e >> 5] = (u32)(b >> 32);
  } else if (bid < 17920) {
    // X f32 [4096][1024] -> packed pre-swizzled bf16 tiles (16384 B each)
    int r2 = bid - 16384;
    int z = r2 >> 9, tl = r2 & 511;         // tl = mb*16 + kt
    const float* X = z == 0 ? Qx : z == 1 ? Kx : Vx;
    unsigned short* P = z == 0 ? qp : z == 1 ? kp : vp;
    int mb = tl >> 4, kt = tl & 15;
    size_t tb = (size_t)tl * 16384;
    #pragma unroll
    for (int i = 0; i < 4; i++) {
      int idx = i * 256 + t;                // 0..1023 = r*8 + j
      int r = idx >> 3, j = idx & 7;
      int c0 = ((j * 16) ^ ((r & 7) << 4)) >> 1;
      const float* src = X + (size_t)(mb * 128 + r) * 1024 + kt * 64 + c0;
      f32x4 a = *(const f32x4*)src;
      f32x4 bq = *(const f32x4*)(src + 4);
      u16x8 o;
      o[0] = f2bf(a[0]); o[1] = f2bf(a[1]); o[2] = f2bf(a[2]); o[3] = f2bf(a[3]);
      o[4] = f2bf(bq[0]); o[5] = f2bf(bq[1]); o[6] = f2bf(bq[2]); o[7] = f2bf(bq[3]);
      *(u16x8*)((char*)P + tb + (size_t)idx * 16) = o;
    }
  } else {
    // W [K][N] f32 -> packed pre-swizzled W^T tiles
    int r2 = bid - 17920;
    int z = r2 >> 10, rem = r2 & 1023;
    const float* W = z == 0 ? W0 : z == 1 ? W1 : z == 2 ? W2 : W3;
    unsigned short* O = z == 0 ? O0 : z == 1 ? O1 : z == 2 ? O2 : O3;
    int tx = t & 31, ty = t >> 5;           // 32 x 8
    int x0 = (rem & 31) * 32, y0 = (rem >> 5) * 32;   // x: n, y: k
    #pragma unroll
    for (int i = 0; i < 4; i++)
      tile[ty + i * 8][tx] = W[(size_t)(y0 + ty + i * 8) * 1024 + x0 + tx];
    __syncthreads();
    #pragma unroll
    for (int i = 0; i < 4; i++) {
      int n = x0 + ty + i * 8, k = y0 + tx;
      size_t a = (size_t)((n >> 7) * 16 + (k >> 6)) * 16384 + swz(n & 127, (k & 63) * 2);
      *(unsigned short*)((char*)O + a) = f2bf(tile[tx][ty + i * 8]);
    }
  }
}

// ---------------- projection GEMM (packed A,B via global_load_lds) ----------------
// z=0: Q -> row-major [B,H,S,dk]; z=1: K -> packed 128kv x 64dk tiles (16KB);
// z=2: V^T -> packed 64d x 128kv tiles (16KB, swzV)
__global__ __launch_bounds__(256) void proj_gemm_k(
    const unsigned short* __restrict__ Qp, const unsigned short* __restrict__ Kp,
    const unsigned short* __restrict__ Vp,
    const unsigned short* __restrict__ Wtq, const unsigned short* __restrict__ Wtk,
    const unsigned short* __restrict__ Wtv,
    unsigned short* __restrict__ qo, unsigned short* __restrict__ ko,
    unsigned short* __restrict__ vo) {
  int z = blockIdx.z;
  const unsigned short* Ap = z == 0 ? Qp : z == 1 ? Kp : Vp;
  const unsigned short* Bp = z == 0 ? Wtq : z == 1 ? Wtk : Wtv;
  unsigned short* out = z == 0 ? qo : z == 1 ? ko : vo;

  __shared__ __align__(16) unsigned short As[8192];
  __shared__ __align__(16) unsigned short Bs[8192];

  int t = threadIdx.x, w = t >> 6, lane = t & 63;
  int wm = (w >> 1) * 64, wn = (w & 1) * 64;
  int rl = lane & 15, kgrp = lane >> 4;

  f32x4 acc[4][4];
  #pragma unroll
  for (int m = 0; m < 4; m++)
    #pragma unroll
    for (int n = 0; n < 4; n++)
      #pragma unroll
      for (int r = 0; r < 4; r++) acc[m][n][r] = 0.f;

  for (int kt = 0; kt < 16; kt++) {
    __syncthreads();
    const char* ab = (const char*)Ap + (size_t)(blockIdx.x * 16 + kt) * 16384 + w * 1024 + lane * 16;
    const char* bb = (const char*)Bp + (size_t)(blockIdx.y * 16 + kt) * 16384 + w * 1024 + lane * 16;
    char* al = (char*)As + w * 1024;
    char* bl = (char*)Bs + w * 1024;
    #pragma unroll
    for (int i = 0; i < 4; i++) {
      gload16(ab + i * 4096, al + i * 4096);
      gload16(bb + i * 4096, bl + i * 4096);
    }
    __syncthreads();
    #pragma unroll
    for (int kk = 0; kk < 2; kk++) {
      bf16x8 af[4], bfr[4];
      #pragma unroll
      for (int m = 0; m < 4; m++)
        af[m] = *(const bf16x8*)((const char*)As + swz(wm + m * 16 + rl, kk * 64 + kgrp * 16));
      #pragma unroll
      for (int n = 0; n < 4; n++)
        bfr[n] = *(const bf16x8*)((const char*)Bs + swz(wn + n * 16 + rl, kk * 64 + kgrp * 16));
      #pragma unroll
      for (int m = 0; m < 4; m++)
        #pragma unroll
        for (int n = 0; n < 4; n++)
          acc[m][n] = __builtin_amdgcn_mfma_f32_16x16x32_bf16(af[m], bfr[n], acc[m][n], 0, 0, 0);
    }
  }
  int m0 = blockIdx.x * 128, n0 = blockIdx.y * 128;
  #pragma unroll
  for (int m = 0; m < 4; m++)
    #pragma unroll
    for (int n = 0; n < 4; n++)
      #pragma unroll
      for (int r = 0; r < 4; r++) {
        int grow = m0 + wm + m * 16 + kgrp * 4 + r;
        int gcol = n0 + wn + n * 16 + rl;
        int b = grow >> 10, s = grow & 1023;
        int h = gcol >> 6, d = gcol & 63;
        unsigned short val = f2bf(acc[m][n][r]);
        if (z == 0) {
          out[(size_t)((b * 16 + h) * 1024 + s) * 64 + d] = val;
        } else if (z == 1) {       // K packed: tile (bh, s>>7), row s&127, col d
          *(unsigned short*)((char*)out +
            (size_t)((b * 16 + h) * 8 + (s >> 7)) * 16384 + swz(s & 127, d * 2)) = val;
        } else {                   // V^T packed: tile (bh, s>>7), row d, col s&127
          *(unsigned short*)((char*)out +
            (size_t)((b * 16 + h) * 8 + (s >> 7)) * 16384 + swzV(d, (s & 127) * 2)) = val;
        }
      }
}

// ---------------- fused masked-causal flash attention (KVBLK=128) ----------------
// No-max softmax; mask bits carry causality. XCD-contiguous block swizzle keeps a
// head's K/V in one L2. Mask words prefetched one iteration ahead. J <= 8 iters.
__global__ __launch_bounds__(256) void attn_k(
    const unsigned short* __restrict__ qg, const unsigned short* __restrict__ kp,
    const unsigned short* __restrict__ vp, const u32* __restrict__ mbits,
    unsigned short* __restrict__ ccp) {
  int bid = blockIdx.x;
  int sw = (bid & 7) * 128 + (bid >> 3);   // XCD-contiguous chunks of 128 blocks
  int bh = sw >> 4;
  int qt = 15 - (sw & 15);                 // heaviest first within chunk
  int b = bh >> 4, h = bh & 15;
  int t = threadIdx.x, w = t >> 6, lane = t & 63;
  int rl = lane & 15, kgrp = lane >> 4;

  const int J = (qt >> 1) + 1;             // kv tiles of 128
  const int q0 = qt * 64;

  __shared__ __align__(16) unsigned short Ks[2][8192];   // [128 kv][64 dk] swz
  __shared__ __align__(16) unsigned short Vs[2][8192];   // [64 d][128 kv] swzV
  __shared__ __align__(16) unsigned short Ps[4][2048];   // per-wave [16 q][128 kv] swzV

  const char* kbase = (const char*)kp + (size_t)bh * 131072;
  const char* vbase = (const char*)vp + (size_t)bh * 131072;

  // Q fragments direct from global (contiguous 16B per lane)
  bf16x8 qa[2];
  {
    int row = q0 + w * 16 + rl;
    #pragma unroll
    for (int kk = 0; kk < 2; kk++)
      qa[kk] = *(const bf16x8*)(qg + (size_t)bh * 65536 + (size_t)row * 64 + kk * 32 + kgrp * 8);
  }

  // prologue: stage tile 0 into buf 0 (each wave stages its 4KB quarter of each)
  {
    const char* kg = kbase + w * 4096 + lane * 16;
    const char* vg = vbase + w * 4096 + lane * 16;
    char* kl = (char*)Ks[0] + w * 4096;
    char* vl = (char*)Vs[0] + w * 4096;
    #pragma unroll
    for (int i = 0; i < 4; i++) {
      gload16(kg + i * 1024, kl + i * 1024);
      gload16(vg + i * 1024, vl + i * 1024);
    }
  }
  // mask words for tile 0 (2 u64 per row = 128 bits kv)
  u64 mcur[4][2];
  #pragma unroll
  for (int r = 0; r < 4; r++) {
    int qrow = q0 + w * 16 + kgrp * 4 + r;
    const u32* mb2 = mbits + (size_t)(b * 1024 + qrow) * 32;
    mcur[r][0] = *(const u64*)(mb2);
    mcur[r][1] = *(const u64*)(mb2 + 2);
  }

  float ls[4];
  f32x4 acc[4];
  #pragma unroll
  for (int r = 0; r < 4; r++) {
    ls[r] = 0.f;
    #pragma unroll
    for (int d = 0; d < 4; d++) acc[d][r] = 0.f;
  }

  for (int j = 0; j < J; j++) {
    __syncthreads();   // tile j resident; prev-iter LDS reads done
    u64 mnext[4][2] = {};
    if (j + 1 < J) {
      int nb = (j + 1) & 1;
      const char* kg = kbase + (size_t)(j + 1) * 16384 + w * 4096 + lane * 16;
      const char* vg = vbase + (size_t)(j + 1) * 16384 + w * 4096 + lane * 16;
      char* kl = (char*)Ks[nb] + w * 4096;
      char* vl = (char*)Vs[nb] + w * 4096;
      #pragma unroll
      for (int i = 0; i < 4; i++) {
        gload16(kg + i * 1024, kl + i * 1024);
        gload16(vg + i * 1024, vl + i * 1024);
      }
      #pragma unroll
      for (int r = 0; r < 4; r++) {
        int qrow = q0 + w * 16 + kgrp * 4 + r;
        const u32* mb2 = mbits + (size_t)(b * 1024 + qrow) * 32 + (size_t)(j + 1) * 4;
        mnext[r][0] = *(const u64*)(mb2);
        mnext[r][1] = *(const u64*)(mb2 + 2);
      }
    }
    const char* Kb = (const char*)Ks[j & 1];
    const char* Vb = (const char*)Vs[j & 1];

    // S = Q K^T over 128 kv (8 col-fragments)
    f32x4 sc[8];
    __builtin_amdgcn_s_setprio(1);
    #pragma unroll
    for (int n = 0; n < 8; n++) {
      f32x4 z4;
      #pragma unroll
      for (int r = 0; r < 4; r++) z4[r] = 0.f;
      bf16x8 kb0 = *(const bf16x8*)(Kb + swz(n * 16 + rl, kgrp * 16));
      bf16x8 kb1 = *(const bf16x8*)(Kb + swz(n * 16 + rl, 64 + kgrp * 16));
      z4 = __builtin_amdgcn_mfma_f32_16x16x32_bf16(qa[0], kb0, z4, 0, 0, 0);
      sc[n] = __builtin_amdgcn_mfma_f32_16x16x32_bf16(qa[1], kb1, z4, 0, 0, 0);
    }
    __builtin_amdgcn_s_setprio(0);

    // p = keep ? exp2(s * 0.125*log2e) : 0 ; write P tile; per-lane row sums
    u64 s0a[4], s1a[4];
    #pragma unroll
    for (int r = 0; r < 4; r++) { s0a[r] = mcur[r][0] >> rl; s1a[r] = mcur[r][1] >> rl; }
    unsigned short* pb = &Ps[w][0];
    const float C = 0.18033688011112042f;   // 0.125 * log2(e)
    #pragma unroll
    for (int n = 0; n < 8; n++) {
      #pragma unroll
      for (int r = 0; r < 4; r++) {
        u32 bit = (u32)(((n < 4 ? s0a[r] : s1a[r]) >> ((n & 3) * 16)) & 1);
        float ex = exp2f(sc[n][r] * C);
        bool keep = bit && (sc[n][r] != 0.f);
        float p = keep ? ex : 0.f;
        ls[r] += p;
        *(unsigned short*)((char*)pb + swzV(kgrp * 4 + r, (n * 16 + rl) * 2)) = f2bf(p);
      }
    }
    // PV: A = P [16q x 128kv], B = V^T rows (output d), K-dim = kv (4 slices)
    bf16x8 pa[4];
    #pragma unroll
    for (int ks = 0; ks < 4; ks++)
      pa[ks] = *(const bf16x8*)((const char*)pb + swzV(rl, ks * 64 + kgrp * 16));
    __builtin_amdgcn_s_setprio(1);
    #pragma unroll
    for (int dd = 0; dd < 4; dd++) {
      #pragma unroll
      for (int ks = 0; ks < 4; ks++) {
        bf16x8 vb = *(const bf16x8*)(Vb + swzV(dd * 16 + rl, ks * 64 + kgrp * 16));
        acc[dd] = __builtin_amdgcn_mfma_f32_16x16x32_bf16(pa[ks], vb, acc[dd], 0, 0, 0);
      }
    }
    __builtin_amdgcn_s_setprio(0);
    #pragma unroll
    for (int r = 0; r < 4; r++) { mcur[r][0] = mnext[r][0]; mcur[r][1] = mnext[r][1]; }
  }
  // epilogue: reduce row sums across the 16-lane group, scale, store packed cc
  #pragma unroll
  for (int r = 0; r < 4; r++) {
    float l = ls[r];
    l += __shfl_xor(l, 1); l += __shfl_xor(l, 2);
    l += __shfl_xor(l, 4); l += __shfl_xor(l, 8);
    float linv = 1.f / l;
    int srow = q0 + w * 16 + kgrp * 4 + r;
    int grow = b * 1024 + srow;
    char* tbase = (char*)ccp + (size_t)((grow >> 7) * 16 + h) * 16384;
    int rr = grow & 127;
    #pragma unroll
    for (int d = 0; d < 4; d++)
      *(unsigned short*)(tbase + swz(rr, (d * 16 + rl) * 2)) = f2bf(acc[d][r] * linv);
  }
}

// ---------------- output GEMM: out = cc(packed) @ Wot^T + bo, f32 out ----------------
__global__ __launch_bounds__(256) void out_gemm_k(
    const unsigned short* __restrict__ Ap, const unsigned short* __restrict__ Bp,
    const float* __restrict__ bias, float* __restrict__ out) {
  __shared__ __align__(16) unsigned short As[8192];
  __shared__ __align__(16) unsigned short Bs[8192];

  int t = threadIdx.x, w = t >> 6, lane = t & 63;
  int wm = (w >> 1) * 64, wn = (w & 1) * 64;
  int rl = lane & 15, kgrp = lane >> 4;

  f32x4 acc[4][4];
  #pragma unroll
  for (int m = 0; m < 4; m++)
    #pragma unroll
    for (int n = 0; n < 4; n++)
      #pragma unroll
      for (int r = 0; r < 4; r++) acc[m][n][r] = 0.f;

  for (int kt = 0; kt < 16; kt++) {
    __syncthreads();
    const char* ab = (const char*)Ap + (size_t)(blockIdx.x * 16 + kt) * 16384 + w * 1024 + lane * 16;
    const char* bb = (const char*)Bp + (size_t)(blockIdx.y * 16 + kt) * 16384 + w * 1024 + lane * 16;
    char* al = (char*)As + w * 1024;
    char* bl = (char*)Bs + w * 1024;
    #pragma unroll
    for (int i = 0; i < 4; i++) {
      gload16(ab + i * 4096, al + i * 4096);
      gload16(bb + i * 4096, bl + i * 4096);
    }
    __syncthreads();
    #pragma unroll
    for (int kk = 0; kk < 2; kk++) {
      bf16x8 af[4], bfr[4];
      #pragma unroll
      for (int m = 0; m < 4; m++)
        af[m] = *(const bf16x8*)((const char*)As + swz(wm + m * 16 + rl, kk * 64 + kgrp * 16));
      #pragma unroll
      for (int n = 0; n < 4; n++)
        bfr[n] = *(const bf16x8*)((const char*)Bs + swz(wn + n * 16 + rl, kk * 64 + kgrp * 16));
      #pragma unroll
      for (int m = 0; m < 4; m++)
        #pragma unroll
        for (int n = 0; n < 4; n++)
          acc[m][n] = __builtin_amdgcn_mfma_f32_16x16x32_bf16(af[m], bfr[n], acc[m][n], 0, 0, 0);
    }
  }
  int m0 = blockIdx.x * 128, n0 = blockIdx.y * 128;
  #pragma unroll
  for (int m = 0; m < 4; m++)
    #pragma unroll
    for (int n = 0; n < 4; n++)
      #pragma unroll
      for (int r = 0; r < 4; r++) {
        int grow = m0 + wm + m * 16 + kgrp * 4 + r;
        int gcol = n0 + wn + n * 16 + rl;
        out[(size_t)grow * 1024 + gcol] = acc[m][n][r] + bias[gcol];
      }
}

extern "C" void kernel_launch(void* const* d_in, const int* in_sizes, int n_in,
                              void* d_out, int out_size, void* d_ws, size_t ws_size,
                              hipStream_t stream) {
  const float* Q  = (const float*)d_in[0];
  const float* K  = (const float*)d_in[1];
  const float* V  = (const float*)d_in[2];
  const int* mask = (const int*)d_in[3];
  const float* Wq = (const float*)d_in[4];
  const float* Wk = (const float*)d_in[5];
  const float* Wv = (const float*)d_in[6];
  const float* Wo = (const float*)d_in[7];
  const float* bo = (const float*)d_in[8];
  float* out = (float*)d_out;

  char* ws = (char*)d_ws;
  unsigned short* xq  = (unsigned short*)(ws);                  // 8 MB packed X_Q (dead after proj)
  unsigned short* xk  = (unsigned short*)(ws + (8u  << 20));    // 8 MB packed X_K
  unsigned short* xv  = (unsigned short*)(ws + (16u << 20));    // 8 MB packed X_V
  unsigned short* ccp = (unsigned short*)(ws);                  // 8 MB packed cc (aliases xq)
  unsigned short* qb  = (unsigned short*)(ws + (24u << 20));    // 8 MB q row-major [B,H,S,dk]
  unsigned short* kpk = (unsigned short*)(ws + (32u << 20));    // 8 MB k packed 128-kv tiles
  unsigned short* vpk = (unsigned short*)(ws + (40u << 20));    // 8 MB v^T packed 128-kv tiles
  unsigned short* wqt = (unsigned short*)(ws + (48u << 20));    // 2 MB each, packed
  unsigned short* wkt = (unsigned short*)(ws + (50u << 20));
  unsigned short* wvt = (unsigned short*)(ws + (52u << 20));
  unsigned short* wot = (unsigned short*)(ws + (54u << 20));
  u32*            mb  = (u32*)(ws + (56u << 20));               // 512 KB

  prep_k<<<22016, 256, 0, stream>>>(mask, mb, Q, K, V, xq, xk, xv,
                                    Wq, Wk, Wv, Wo, wqt, wkt, wvt, wot);
  proj_gemm_k<<<dim3(32, 8, 3), 256, 0, stream>>>(xq, xk, xv, wqt, wkt, wvt, qb, kpk, vpk);
  attn_k<<<1024, 256, 0, stream>>>(qb, kpk, vpk, mb, ccp);
  out_gemm_k<<<dim3(32, 8), 256, 0, stream>>>(ccp, wot, bo, out);
}